// Round 1
// baseline (616.067 us; speedup 1.0000x reference)
//
#include <hip/hip_runtime.h>

// Quantize_78365973283370: VQ with argmax (faithful source bug: farthest cluster).
// inputs: d_in[0] = inputs [8,32,32,128] f32 (N=8192 samples x D=128)
//         d_in[1] = cluster_mean [128,10000] f32  (column e = cluster vector)
// out (concat f32): quantize [8192*128] | cluster_index [8192] (as float) | diff [8192]
// ws: sT (f64 transposed samples, 8 MB) | s2 (f64, 64 KB) | c2 (f64, 80 KB)

#define NSAMP 8192
#define NEMB  10000
#define DIM   128
#define NS    8     // samples per block
#define NE    4     // cluster columns per thread
#define TPB   256

__global__ __launch_bounds__(TPB) void prep_transpose(const float* __restrict__ smp,
                                                      double* __restrict__ sT) {
    int gid = blockIdx.x * TPB + threadIdx.x;      // 0 .. NSAMP*DIM-1
    int d = gid >> 13;                              // gid / 8192
    int n = gid & (NSAMP - 1);
    sT[gid] = (double)smp[n * DIM + d];             // sT[d][n]
}

__global__ __launch_bounds__(TPB) void prep_s2(const float* __restrict__ smp,
                                               double* __restrict__ s2) {
    int n = blockIdx.x * TPB + threadIdx.x;
    double a = 0.0;
#pragma unroll 8
    for (int d = 0; d < DIM; ++d) {
        double v = (double)smp[n * DIM + d];
        a = fma(v, v, a);
    }
    s2[n] = a;
}

__global__ __launch_bounds__(TPB) void prep_c2(const float* __restrict__ cm,
                                               double* __restrict__ c2) {
    int e = blockIdx.x * TPB + threadIdx.x;
    if (e >= NEMB) return;
    double a = 0.0;
#pragma unroll 8
    for (int d = 0; d < DIM; ++d) {
        double v = (double)cm[(size_t)d * NEMB + e];
        a = fma(v, v, a);
    }
    c2[e] = a;
}

__global__ __launch_bounds__(TPB) void vq_main(
    const float* __restrict__ cm, const float* __restrict__ smp,
    const double* __restrict__ sT, const double* __restrict__ s2,
    const double* __restrict__ c2,
    float* __restrict__ out_q, float* __restrict__ out_idx, float* __restrict__ out_diff)
{
    const int tid = threadIdx.x;
    const int s0 = blockIdx.x * NS;

    double best[NS];
    int    bestE[NS];
#pragma unroll
    for (int s = 0; s < NS; ++s) { best[s] = -1.0e300; bestE[s] = 0; }

    // hoist per-sample ||s||^2 (uniform -> SGPRs)
    double s2v[NS];
#pragma unroll
    for (int s = 0; s < NS; ++s) s2v[s] = s2[s0 + s];

    for (int e0 = 0; e0 < NEMB; e0 += TPB * NE) {
        const int ebase = e0 + tid;
        const float* p[NE];
#pragma unroll
        for (int k = 0; k < NE; ++k) {
            int col = ebase + k * TPB;
            if (col > NEMB - 1) col = NEMB - 1;    // clamp (tail chunk); guarded below
            p[k] = cm + col;
        }

        double acc[NS][NE];
#pragma unroll
        for (int s = 0; s < NS; ++s)
#pragma unroll
            for (int k = 0; k < NE; ++k) acc[s][k] = 0.0;

#pragma unroll 2
        for (int d = 0; d < DIM; ++d) {
            double cv[NE];
#pragma unroll
            for (int k = 0; k < NE; ++k) cv[k] = (double)p[k][(size_t)d * NEMB];
            const double* sd = sT + (size_t)d * NSAMP + s0;   // uniform -> s_load
#pragma unroll
            for (int s = 0; s < NS; ++s) {
                double sv = sd[s];
#pragma unroll
                for (int k = 0; k < NE; ++k) acc[s][k] = fma(cv[k], sv, acc[s][k]);
            }
        }

#pragma unroll
        for (int k = 0; k < NE; ++k) {
            int e = ebase + k * TPB;
            if (e < NEMB) {
                double ce = c2[e];
#pragma unroll
                for (int s = 0; s < NS; ++s) {
                    double dist = fma(-2.0, acc[s][k], s2v[s] + ce);
                    if (dist > best[s]) { best[s] = dist; bestE[s] = e; }   // strict >: first max
                }
            }
        }
    }

    // wave-level butterfly reduce: max value, tie -> smaller index
#pragma unroll
    for (int s = 0; s < NS; ++s) {
#pragma unroll
        for (int m = 1; m < 64; m <<= 1) {
            double ov = __shfl_xor(best[s], m, 64);
            int    oe = __shfl_xor(bestE[s], m, 64);
            if (ov > best[s] || (ov == best[s] && oe < bestE[s])) { best[s] = ov; bestE[s] = oe; }
        }
    }

    __shared__ double wv[TPB / 64][NS];
    __shared__ int    we[TPB / 64][NS];
    __shared__ int    fin[NS];
    const int lane = tid & 63, wav = tid >> 6;
    if (lane == 0) {
#pragma unroll
        for (int s = 0; s < NS; ++s) { wv[wav][s] = best[s]; we[wav][s] = bestE[s]; }
    }
    __syncthreads();
    if (tid < NS) {
        const int s = tid;
        double bv = wv[0][s]; int be = we[0][s];
#pragma unroll
        for (int w = 1; w < TPB / 64; ++w) {
            double v = wv[w][s]; int e = we[w][s];
            if (v > bv || (v == bv && e < be)) { bv = v; be = e; }
        }
        fin[s] = be;
        out_idx[s0 + s] = (float)be;     // index written as float value
    }
    __syncthreads();

    // gather quantize + diff: 32 threads per sample, 4 dims each
    {
        const int s  = tid >> 5;
        const int d0 = (tid & 31) * 4;
        const int e  = fin[s];
        float a = 0.0f;
#pragma unroll
        for (int j = 0; j < 4; ++j) {
            int d = d0 + j;
            float q = cm[(size_t)d * NEMB + e];
            float x = smp[(size_t)(s0 + s) * DIM + d];
            out_q[(size_t)(s0 + s) * DIM + d] = q;
            float t = x - q;
            a = fmaf(t, t, a);
        }
#pragma unroll
        for (int m = 1; m < 32; m <<= 1) a += __shfl_xor(a, m, 64);
        if ((tid & 31) == 0) out_diff[s0 + s] = a * (1.0f / DIM);
    }
}

extern "C" void kernel_launch(void* const* d_in, const int* in_sizes, int n_in,
                              void* d_out, int out_size, void* d_ws, size_t ws_size,
                              hipStream_t stream) {
    const float* smp = (const float*)d_in[0];   // inputs [8192,128]
    const float* cm  = (const float*)d_in[1];   // cluster_mean [128,10000]

    float* out      = (float*)d_out;
    float* out_q    = out;                          // 8192*128
    float* out_idx  = out + (size_t)NSAMP * DIM;    // 8192
    float* out_diff = out_idx + NSAMP;              // 8192

    char* ws = (char*)d_ws;
    double* sT = (double*)ws;                                        // 8 MB
    double* s2 = (double*)(ws + (size_t)NSAMP * DIM * 8);            // 64 KB
    double* c2 = (double*)(ws + (size_t)NSAMP * DIM * 8 + (size_t)NSAMP * 8); // 80 KB

    prep_transpose<<<NSAMP * DIM / TPB, TPB, 0, stream>>>(smp, sT);
    prep_s2<<<NSAMP / TPB, TPB, 0, stream>>>(smp, s2);
    prep_c2<<<(NEMB + TPB - 1) / TPB, TPB, 0, stream>>>(cm, c2);
    vq_main<<<NSAMP / NS, TPB, 0, stream>>>(cm, smp, sT, s2, c2, out_q, out_idx, out_diff);
}